// Round 13
// baseline (1123.355 us; speedup 1.0000x reference)
//
#include <hip/hip_runtime.h>
#include <hip/hip_bf16.h>
#include <stdint.h>

// ---- problem dims (fixed by setup_inputs) ----
#define DIM   4096
#define HID   11008
#define MTOK  4096              // B*S = 2*2048
#define NELW  (HID * DIM)       // 45,088,768 elements per weight matrix

typedef __bf16 bf16x8 __attribute__((ext_vector_type(8)));
typedef float  f32x4  __attribute__((ext_vector_type(4)));
using gptr_t = const __attribute__((address_space(1))) void*;
using lptr_t = __attribute__((address_space(3))) void*;

__device__ __forceinline__ float bf2f(unsigned short u) {
    unsigned int t = ((unsigned int)u) << 16;
    float f; __builtin_memcpy(&f, &t, 4); return f;
}
__device__ __forceinline__ unsigned short f2bf(float f) {   // RNE
    unsigned int x; __builtin_memcpy(&x, &f, 4);
    x += 0x7fffu + ((x >> 16) & 1u);
    return (unsigned short)(x >> 16);
}

__device__ __constant__ float NF4_TAB[16] = {
    -1.0f, -0.6961928009986877f, -0.5250730514526367f, -0.39491748809814453f,
    -0.28444138169288635f, -0.18477343022823334f, -0.09105003625154495f, 0.0f,
    0.07958029955625534f, 0.16093020141124725f, 0.24611230194568634f,
    0.33791524171829224f, 0.44070982933044434f, 0.5626170039176941f,
    0.6989939212799072f, 1.0f};

// dequant 8 codes at element offset `base` (table via wave shfl from lanes 0-15)
__device__ __forceinline__ void dq8(const int* codes, const float* absmax,
                                    unsigned short* out, long base, float tv)
{
    int4 c0 = *(const int4*)(codes + base);
    int4 c1 = *(const int4*)(codes + base + 4);
    float s = absmax[base >> 6];
    union { uint4 q; unsigned short u[8]; } o;
    o.u[0] = f2bf(__shfl(tv, c0.x) * s);
    o.u[1] = f2bf(__shfl(tv, c0.y) * s);
    o.u[2] = f2bf(__shfl(tv, c0.z) * s);
    o.u[3] = f2bf(__shfl(tv, c0.w) * s);
    o.u[4] = f2bf(__shfl(tv, c1.x) * s);
    o.u[5] = f2bf(__shfl(tv, c1.y) * s);
    o.u[6] = f2bf(__shfl(tv, c1.z) * s);
    o.u[7] = f2bf(__shfl(tv, c1.w) * s);
    *(uint4*)(out + base) = o.q;
}

// preamble: blocks [0, 22016) dequant W1; blocks [22016, 30208) cast x->bf16
#define W1BLK 22016
#define PREBLK (W1BLK + (MTOK * DIM) / 2048)
__global__ __launch_bounds__(256) void pre_k(
    const int* __restrict__ w1c, const float* __restrict__ w1a,
    unsigned short* __restrict__ W1,
    const float* __restrict__ x, unsigned short* __restrict__ Xb)
{
    float tv = NF4_TAB[threadIdx.x & 15];
    if ((int)blockIdx.x < W1BLK) {
        long base = ((long)blockIdx.x * 256 + threadIdx.x) * 8;
        dq8(w1c, w1a, W1, base, tv);
    } else {
        long base = ((long)(blockIdx.x - W1BLK) * 256 + threadIdx.x) * 8;
        float4 a = *(const float4*)(x + base);
        float4 b = *(const float4*)(x + base + 4);
        union { uint4 q; unsigned short u[8]; } o;
        o.u[0] = f2bf(a.x); o.u[1] = f2bf(a.y); o.u[2] = f2bf(a.z); o.u[3] = f2bf(a.w);
        o.u[4] = f2bf(b.x); o.u[5] = f2bf(b.y); o.u[6] = f2bf(b.z); o.u[7] = f2bf(b.w);
        *(uint4*)(Xb + base) = o.q;
    }
}

// ============================================================================
// 256x256-tile GEMM, R13 = R10's VERIFIED ledger + m201 phase discipline.
//
// R11/R12 FAILURE ROOT CAUSE (found r12 post-mortem): LDS regions are split
// by M-half (h=wm: A rows 0-127 / 128-255) and N-half (g=wn>>1), NOT by
// fragment set.  a0/a1 are SUB-ROWS of ONE region (which*64+...), b0/b1
// sub-cols of one region.  R11's ph1 stage of region h=0 overwrote rows
// 64-127 that waves 0-3 read as a1[t] at ph2 (race); ph2's B0-stage likewise
// raced ph3's b1[t] reads.  R10's stage placement has no such hazard.
//
// R13 keeps R10's stage placement + vmcnt ledger EXACTLY (hardware-verified
// passing in R9/R10):
//   prologue: tile0 A0,A1,B0,B1 -> buf0; tile1 A0,A1 -> buf1 (12 loads);
//     vmcnt(4) lands tile0; BAR; LDA(a0,0,0).
//   iter t: P1 stage B0[t+1]->nb, P2 B1[t+1]->nb, P3 A0[t+2]->pb + vmcnt(6)
//     publishes A[t+1], P4 A1[t+2]->pb + vmcnt(4) publishes B[t+1].
//     In-flight never <4.
//   Region liveness: P3's A0-stage after P2's LGKM0 (a1[t] drained, both
//     halves) + BAR; P4's A1-stage likewise; P1/P2 B-stages -> buf[nb]
//     B-regions dead since t-1 P3; P4's a0[t+1] read after P3's publish BAR.
//   Tail: P3/P4 clamp to NT-1 -> dupes into dead pb A-regions.  Epilogue
//     tile NT-1 barrier-free (published at NT-2 P4's vmcnt+BAR).  NT>=3 ✓.
//
// CHANGED vs R10 (the R11 theory, now race-free): phase discipline
//   {LD; STAGE; s_barrier; lgkmcnt(0)+sched_barrier; setprio MMA; s_barrier}
// All-or-nothing lgkm drain after the barrier staggers waves (first-drained
// wave runs its clean MFMA cluster while others wait) -> cross-wave DS/MFMA
// overlap; setprio protects the MFMA-ing wave (T5).  a1 read sits in its own
// phase P2 (consumed by P2's MMA after its LGKM0).
//
// Blocks >= ngemm: grid-stride NF4 dequant tail (consumer = next dispatch).
// MODE: 0 = f32 out, 1 = bf16 out, 2 = bf16 fused h=silu(Cout)*acc in-place.
// ============================================================================
template<int MODE>
__global__ __launch_bounds__(512, 2) void gemm256_k(
    const unsigned short* __restrict__ A, const unsigned short* __restrict__ B,
    void* __restrict__ Cout, int M, int N, int K, int ngemm,
    const int* __restrict__ dqc, const float* __restrict__ dqa,
    unsigned short* __restrict__ dqo)
{
    __shared__ __align__(16) unsigned short lds[2][2][2][128 * 64];

    const int tid = threadIdx.x;
    const int lane = tid & 63;

    if ((int)blockIdx.x >= ngemm) {          // ---- tail: grid-stride dequant
        if (!dqo) return;
        const int b = (int)blockIdx.x - ngemm;
        const int ndq = (int)gridDim.x - ngemm;
        const long stride = (long)ndq * 512 * 8;
        float tv = NF4_TAB[lane & 15];
        for (long base = ((long)b * 512 + tid) * 8; base < (long)NELW; base += stride)
            dq8(dqc, dqa, dqo, base, tv);
        return;
    }

    const int w = tid >> 6;
    const int wm = w >> 2, wn = w & 3;           // 2M x 4N wave grid
    const int lrow = lane & 15, hi = lane >> 4;
    const int key = lrow & 7;                    // read-side swizzle key

    const int nbm = M >> 8, nbn = N >> 8;
    const int cpx = (nbm * nbn) >> 3;            // ngemm%8==0 -> bijective
    int swz = ((int)blockIdx.x & 7) * cpx + ((int)blockIdx.x >> 3);
    const int bm = swz % nbm, bn = swz / nbm;    // bm fastest: B-panel reuse

    const long ldK = K;
    const int srow = tid >> 3;                   // 0..63 staging row
    const int scol = ((tid & 7) ^ (srow & 7)) * 8;   // pre-swizzled source col
    const unsigned short* gA = A + ((long)(bm * 256 + srow)) * ldK + scol;
    const unsigned short* gB = B + ((long)(bn * 256 + srow)) * ldK + scol;

    f32x4 acc[8][4];
    #pragma unroll
    for (int m = 0; m < 8; ++m)
        #pragma unroll
        for (int n = 0; n < 4; ++n) acc[m][n] = f32x4{0.f, 0.f, 0.f, 0.f};

    bf16x8 a0[4][2], a1[4][2], b0[2][2], b1[2][2];

    // stage half-tile h (0=A rows0-127, 1=A rows128-255, 2=B0, 3=B1) of K-tile
    auto STAGE = [&](int kt, int h, int b) {
        const unsigned short* src = ((h >> 1) ? gB : gA)
            + (long)((h & 1) * 128) * ldK + (long)kt * 64;
        char* dst = (char*)&lds[b][h >> 1][h & 1][0] + w * 1024;
        __builtin_amdgcn_global_load_lds((gptr_t)src, (lptr_t)dst, 16, 0, 0);
        __builtin_amdgcn_global_load_lds((gptr_t)(src + (long)64 * ldK),
                                         (lptr_t)(dst + 8192), 16, 0, 0);
    };
    // lane's A fragments: which=0 -> rows 0-63 of wave's half, 1 -> rows 64-127
    auto LDA = [&](bf16x8 (&fr)[4][2], int which, int b) {
        const unsigned short* base = &lds[b][0][wm][0];
        #pragma unroll
        for (int m = 0; m < 4; ++m)
            #pragma unroll
            for (int ks = 0; ks < 2; ++ks)
                fr[m][ks] = *(const bf16x8*)(base + (which * 64 + m * 16 + lrow) * 64
                                             + (((ks * 4 + hi) ^ key) * 8));
    };
    // lane's B fragments: which=0 -> n0..1, 1 -> n2..3
    auto LDB = [&](bf16x8 (&fr)[2][2], int which, int b) {
        const unsigned short* base = &lds[b][1][wn >> 1][0];
        #pragma unroll
        for (int n = 0; n < 2; ++n)
            #pragma unroll
            for (int ks = 0; ks < 2; ++ks)
                fr[n][ks] = *(const bf16x8*)(base + ((wn & 1) * 64 + (which * 2 + n) * 16 + lrow) * 64
                                             + (((ks * 4 + hi) ^ key) * 8));
    };
    auto MMA = [&](bf16x8 (&fa)[4][2], bf16x8 (&fb)[2][2], int mo, int no) {
        __builtin_amdgcn_s_setprio(1);
        #pragma unroll
        for (int m = 0; m < 4; ++m)
            #pragma unroll
            for (int n = 0; n < 2; ++n)
                #pragma unroll
                for (int ks = 0; ks < 2; ++ks)
                    acc[mo + m][no + n] = __builtin_amdgcn_mfma_f32_16x16x32_bf16(
                        fa[m][ks], fb[n][ks], acc[mo + m][no + n], 0, 0, 0);
        __builtin_amdgcn_s_setprio(0);
    };
    #define BAR()   do { __builtin_amdgcn_s_barrier(); \
                         __builtin_amdgcn_sched_barrier(0); } while (0)
    #define LGKM0() do { asm volatile("s_waitcnt lgkmcnt(0)" ::: "memory"); \
                         __builtin_amdgcn_sched_barrier(0); } while (0)

    const int NT = K >> 6;
    // ---- prologue (R10-identical): tile0 full -> buf0; tile1 A-halves -> buf1
    STAGE(0, 0, 0); STAGE(0, 1, 0); STAGE(0, 2, 0); STAGE(0, 3, 0);
    STAGE(1, 0, 1); STAGE(1, 1, 1);
    asm volatile("s_waitcnt vmcnt(4)" ::: "memory");   // tile0's 8 loads landed
    BAR();
    LDA(a0, 0, 0);

    int cur = 0;
    for (int t = 0; t < NT - 1; ++t) {
        const int nb = cur ^ 1;
        const int tA = (t + 2 < NT) ? t + 2 : NT - 1;  // clamp: dupes land dead
        // P1: read b0[t]; stage B0[t+1]->nb; drain; MMA(a0,b0)
        LDB(b0, 0, cur);
        STAGE(t + 1, 2, nb);
        BAR(); LGKM0();
        MMA(a0, b0, 0, 0);
        BAR();
        // P2: read a1[t]; stage B1[t+1]->nb; drain; MMA(a1,b0)
        LDA(a1, 1, cur);
        STAGE(t + 1, 3, nb);
        BAR(); LGKM0();
        MMA(a1, b0, 4, 0);
        BAR();
        // P3: read b1[t]; stage A0[t+2]->cur; drain; MMA(a0,b1); publish A[t+1]
        LDB(b1, 1, cur);
        STAGE(tA, 0, cur);
        BAR(); LGKM0();
        MMA(a0, b1, 0, 2);
        asm volatile("s_waitcnt vmcnt(6)" ::: "memory");
        BAR();
        // P4: read a0[t+1] (published at P3); stage A1[t+2]->cur; drain;
        //     MMA(a1,b1); publish B[t+1]
        LDA(a0, 0, nb);
        STAGE(tA, 1, cur);
        BAR(); LGKM0();
        MMA(a1, b1, 4, 2);
        asm volatile("s_waitcnt vmcnt(4)" ::: "memory");
        BAR();
        cur = nb;
    }
    // ---- epilogue: last tile, fully published by final P3/P4 waits ----
    LDB(b0, 0, cur);
    MMA(a0, b0, 0, 0);
    LDA(a1, 1, cur);
    MMA(a1, b0, 4, 0);
    LDB(b1, 1, cur);
    MMA(a0, b1, 0, 2);
    MMA(a1, b1, 4, 2);
    #undef BAR
    #undef LGKM0

    // ---- C write.  C/D layout: col = lane&15, row = (lane>>4)*4 + reg ----
    const int grow = bm * 256 + wm * 128 + hi * 4;
    const int gcol = bn * 256 + wn * 64 + lrow;
    if (MODE == 0) {
        float* C = (float*)Cout;
        #pragma unroll
        for (int m = 0; m < 8; ++m)
            #pragma unroll
            for (int n = 0; n < 4; ++n)
                #pragma unroll
                for (int r = 0; r < 4; ++r)
                    C[(long)(grow + m * 16 + r) * N + gcol + n * 16] = acc[m][n][r];
    } else if (MODE == 1) {
        unsigned short* C = (unsigned short*)Cout;
        #pragma unroll
        for (int m = 0; m < 8; ++m)
            #pragma unroll
            for (int n = 0; n < 4; ++n)
                #pragma unroll
                for (int r = 0; r < 4; ++r)
                    C[(long)(grow + m * 16 + r) * N + gcol + n * 16] = f2bf(acc[m][n][r]);
    } else {
        // fused SwiGLU: C holds h1 (bf16); acc = h3. write silu(h1)*h3 in place
        unsigned short* C = (unsigned short*)Cout;
        #pragma unroll
        for (int m = 0; m < 8; ++m)
            #pragma unroll
            for (int n = 0; n < 4; ++n)
                #pragma unroll
                for (int r = 0; r < 4; ++r) {
                    long idx = (long)(grow + m * 16 + r) * N + gcol + n * 16;
                    float h1v = bf2f(C[idx]);
                    float g = h1v / (1.0f + __expf(-h1v));
                    C[idx] = f2bf(g * acc[m][n][r]);
                }
    }
}

// ---- workspace layout (bytes) ----
//  [0)          W1 bf16 (90,177,536)
//  [90177536)   W3 bf16 (90,177,536)  -- later reused for W2
//  [180355072)  x  bf16 (33,554,432)
//  [213909504)  h1 bf16 (90,177,536)  -- fused swiglu written in-place by GEMM2
//  total 304,087,040
#define WS_NEEDED 304087040UL
#define DQBLK 512     // tail dequant blocks appended to GEMM1/GEMM2 dispatches

extern "C" void kernel_launch(void* const* d_in, const int* in_sizes, int n_in,
                              void* d_out, int out_size, void* d_ws, size_t ws_size,
                              hipStream_t stream) {
    const float* x   = (const float*)d_in[0];
    const int*   w1c = (const int*)d_in[1];
    const float* w1a = (const float*)d_in[2];
    const int*   w2c = (const int*)d_in[3];
    const float* w2a = (const float*)d_in[4];
    const int*   w3c = (const int*)d_in[5];
    const float* w3a = (const float*)d_in[6];

    if (ws_size < WS_NEEDED) return;   // fail loudly via validation

    char* ws = (char*)d_ws;
    unsigned short* W1 = (unsigned short*)(ws);
    unsigned short* W3 = (unsigned short*)(ws + 90177536);   // also W2 later
    unsigned short* Xb = (unsigned short*)(ws + 180355072);
    unsigned short* H1 = (unsigned short*)(ws + 213909504);

    // preamble: W1 dequant + x cast (one dispatch)
    pre_k<<<PREBLK, 256, 0, stream>>>(w1c, w1a, W1, x, Xb);

    const int g12 = (MTOK / 256) * (HID / 256);   // 688
    const int g3  = (MTOK / 256) * (DIM / 256);   // 256

    // h1 = x @ W1^T; tail blocks dequant W3 -> consumed by NEXT dispatch
    gemm256_k<1><<<g12 + DQBLK, 512, 0, stream>>>(Xb, W1, H1, MTOK, HID, DIM,
                                                  g12, w3c, w3a, W3);
    // h = silu(h1) * (x @ W3^T) in-place; tail blocks dequant W2 into W1's buf
    // (GEMM1 retired at dispatch boundary; this dispatch reads only Xb/W3/H1)
    gemm256_k<2><<<g12 + DQBLK, 512, 0, stream>>>(Xb, W3, H1, MTOK, HID, DIM,
                                                  g12, w2c, w2a, W1);
    // out = h @ W2^T (W2 lives in W1's buffer), fp32 output
    gemm256_k<0><<<g3, 512, 0, stream>>>(H1, W1, (float*)d_out, MTOK, DIM, HID,
                                         g3, nullptr, nullptr, nullptr);
}

// Round 14
// 1107.631 us; speedup vs baseline: 1.0142x; 1.0142x over previous
//
#include <hip/hip_runtime.h>
#include <hip/hip_bf16.h>
#include <stdint.h>

// ---- problem dims (fixed by setup_inputs) ----
#define DIM   4096
#define HID   11008
#define MTOK  4096              // B*S = 2*2048
#define NELW  (HID * DIM)       // 45,088,768 elements per weight matrix

typedef __bf16 bf16x8 __attribute__((ext_vector_type(8)));
typedef float  f32x4  __attribute__((ext_vector_type(4)));
using gptr_t = const __attribute__((address_space(1))) void*;
using lptr_t = __attribute__((address_space(3))) void*;

__device__ __forceinline__ float bf2f(unsigned short u) {
    unsigned int t = ((unsigned int)u) << 16;
    float f; __builtin_memcpy(&f, &t, 4); return f;
}
__device__ __forceinline__ unsigned short f2bf(float f) {   // RNE
    unsigned int x; __builtin_memcpy(&x, &f, 4);
    x += 0x7fffu + ((x >> 16) & 1u);
    return (unsigned short)(x >> 16);
}

__device__ __constant__ float NF4_TAB[16] = {
    -1.0f, -0.6961928009986877f, -0.5250730514526367f, -0.39491748809814453f,
    -0.28444138169288635f, -0.18477343022823334f, -0.09105003625154495f, 0.0f,
    0.07958029955625534f, 0.16093020141124725f, 0.24611230194568634f,
    0.33791524171829224f, 0.44070982933044434f, 0.5626170039176941f,
    0.6989939212799072f, 1.0f};

// dequant 8 codes at element offset `base` (table via wave shfl from lanes 0-15)
__device__ __forceinline__ void dq8(const int* codes, const float* absmax,
                                    unsigned short* out, long base, float tv)
{
    int4 c0 = *(const int4*)(codes + base);
    int4 c1 = *(const int4*)(codes + base + 4);
    float s = absmax[base >> 6];
    union { uint4 q; unsigned short u[8]; } o;
    o.u[0] = f2bf(__shfl(tv, c0.x) * s);
    o.u[1] = f2bf(__shfl(tv, c0.y) * s);
    o.u[2] = f2bf(__shfl(tv, c0.z) * s);
    o.u[3] = f2bf(__shfl(tv, c0.w) * s);
    o.u[4] = f2bf(__shfl(tv, c1.x) * s);
    o.u[5] = f2bf(__shfl(tv, c1.y) * s);
    o.u[6] = f2bf(__shfl(tv, c1.z) * s);
    o.u[7] = f2bf(__shfl(tv, c1.w) * s);
    *(uint4*)(out + base) = o.q;
}

// preamble: blocks [0, 22016) dequant W1; blocks [22016, 30208) cast x->bf16
#define W1BLK 22016
#define PREBLK (W1BLK + (MTOK * DIM) / 2048)
__global__ __launch_bounds__(256) void pre_k(
    const int* __restrict__ w1c, const float* __restrict__ w1a,
    unsigned short* __restrict__ W1,
    const float* __restrict__ x, unsigned short* __restrict__ Xb)
{
    float tv = NF4_TAB[threadIdx.x & 15];
    if ((int)blockIdx.x < W1BLK) {
        long base = ((long)blockIdx.x * 256 + threadIdx.x) * 8;
        dq8(w1c, w1a, W1, base, tv);
    } else {
        long base = ((long)(blockIdx.x - W1BLK) * 256 + threadIdx.x) * 8;
        float4 a = *(const float4*)(x + base);
        float4 b = *(const float4*)(x + base + 4);
        union { uint4 q; unsigned short u[8]; } o;
        o.u[0] = f2bf(a.x); o.u[1] = f2bf(a.y); o.u[2] = f2bf(a.z); o.u[3] = f2bf(a.w);
        o.u[4] = f2bf(b.x); o.u[5] = f2bf(b.y); o.u[6] = f2bf(b.z); o.u[7] = f2bf(b.w);
        *(uint4*)(Xb + base) = o.q;
    }
}

// ============================================================================
// 256x256-tile 4-phase/K-tile GEMM — R14 = R10 verbatim (session best, 1104us).
//
// Verified-best configuration after the R11-R13 arc refuted the m201
// phase-discipline theory (all-or-nothing lgkm drain / wave stagger: null).
// Single barrier per phase (R9, +2%), a1-read re-phased into P1 (R10, +1%),
// sched_barrier mask 0xF (memory classes pinned, ALU/VALU/SALU/MFMA free).
//
// vmcnt LEDGER (r3/r4-derived, HW-verified passing in R9/R10):
//   prologue: tile0 A0,A1,B0,B1 -> buf0; tile1 A0,A1 -> buf1 (12 loads);
//     vmcnt(4) lands tile0; BAR; LDA(a0,0,0).
//   iter t: P1 stage B0[t+1]->nb, P2 B1[t+1]->nb, P3 A0[t+2]->cur + vmcnt(6)
//     publishes A[t+1], P4 A1[t+2]->cur + vmcnt(4) publishes B[t+1].
//     In-flight never <4 (T4).
//   Region liveness (regions = M-half for A, N-pair for B — R12 lesson):
//     P3's A0-stage: a1[t] (rows 64-127, same region) read at P2, drained by
//     P2's consuming MMA before P2's barrier -> 1 bar before stage.  P4's
//     A1-stage likewise.  P1/P2 B-stages -> buf[nb] B-regions dead since t-1
//     P3.  P4's a0[t+1] read follows P3's vmcnt(6)+BAR publish.
//   Tail: P3/P4 clamp to NT-1 -> dupes land in dead opposite-parity regions.
//   Epilogue tile: fully published by final P3/P4 waits; compiler-managed lgkm.
//
// Blocks >= ngemm run grid-stride NF4 dequant (dqc/dqa->dqo) -- tail fill;
// consumer is the NEXT dispatch (dispatch boundary = fence).
// MODE: 0 = f32 out, 1 = bf16 out, 2 = bf16 fused h=silu(Cout)*acc in-place.
// ============================================================================
template<int MODE>
__global__ __launch_bounds__(512, 2) void gemm256_k(
    const unsigned short* __restrict__ A, const unsigned short* __restrict__ B,
    void* __restrict__ Cout, int M, int N, int K, int ngemm,
    const int* __restrict__ dqc, const float* __restrict__ dqa,
    unsigned short* __restrict__ dqo)
{
    __shared__ __align__(16) unsigned short lds[2][2][2][128 * 64];

    const int tid = threadIdx.x;
    const int lane = tid & 63;

    if ((int)blockIdx.x >= ngemm) {          // ---- tail: grid-stride dequant
        if (!dqo) return;
        const int b = (int)blockIdx.x - ngemm;
        const int ndq = (int)gridDim.x - ngemm;
        const long stride = (long)ndq * 512 * 8;
        float tv = NF4_TAB[lane & 15];
        for (long base = ((long)b * 512 + tid) * 8; base < (long)NELW; base += stride)
            dq8(dqc, dqa, dqo, base, tv);
        return;
    }

    const int w = tid >> 6;
    const int wm = w >> 2, wn = w & 3;           // 2M x 4N wave grid
    const int lrow = lane & 15, hi = lane >> 4;
    const int key = lrow & 7;                    // read-side swizzle key

    const int nbm = M >> 8, nbn = N >> 8;
    const int cpx = (nbm * nbn) >> 3;            // ngemm%8==0 -> bijective
    int swz = ((int)blockIdx.x & 7) * cpx + ((int)blockIdx.x >> 3);
    const int bm = swz % nbm, bn = swz / nbm;    // bm fastest: B-panel reuse

    const long ldK = K;
    const int srow = tid >> 3;                   // 0..63 staging row
    const int scol = ((tid & 7) ^ (srow & 7)) * 8;   // pre-swizzled source col
    const unsigned short* gA = A + ((long)(bm * 256 + srow)) * ldK + scol;
    const unsigned short* gB = B + ((long)(bn * 256 + srow)) * ldK + scol;

    f32x4 acc[8][4];
    #pragma unroll
    for (int m = 0; m < 8; ++m)
        #pragma unroll
        for (int n = 0; n < 4; ++n) acc[m][n] = f32x4{0.f, 0.f, 0.f, 0.f};

    bf16x8 a0[4][2], a1[4][2], b0[2][2], b1[2][2];

    // stage half-tile h (0=A rows0-127, 1=A rows128-255, 2=B0, 3=B1) of K-tile
    auto STAGE = [&](int kt, int h, int b) {
        const unsigned short* src = ((h >> 1) ? gB : gA)
            + (long)((h & 1) * 128) * ldK + (long)kt * 64;
        char* dst = (char*)&lds[b][h >> 1][h & 1][0] + w * 1024;
        __builtin_amdgcn_global_load_lds((gptr_t)src, (lptr_t)dst, 16, 0, 0);
        __builtin_amdgcn_global_load_lds((gptr_t)(src + (long)64 * ldK),
                                         (lptr_t)(dst + 8192), 16, 0, 0);
    };
    // lane's A fragments: which=0 -> rows 0-63 of wave's half, 1 -> rows 64-127
    auto LDA = [&](bf16x8 (&fr)[4][2], int which, int b) {
        const unsigned short* base = &lds[b][0][wm][0];
        #pragma unroll
        for (int m = 0; m < 4; ++m)
            #pragma unroll
            for (int ks = 0; ks < 2; ++ks)
                fr[m][ks] = *(const bf16x8*)(base + (which * 64 + m * 16 + lrow) * 64
                                             + (((ks * 4 + hi) ^ key) * 8));
    };
    // lane's B fragments: which=0 -> n0..1, 1 -> n2..3
    auto LDB = [&](bf16x8 (&fr)[2][2], int which, int b) {
        const unsigned short* base = &lds[b][1][wn >> 1][0];
        #pragma unroll
        for (int n = 0; n < 2; ++n)
            #pragma unroll
            for (int ks = 0; ks < 2; ++ks)
                fr[n][ks] = *(const bf16x8*)(base + ((wn & 1) * 64 + (which * 2 + n) * 16 + lrow) * 64
                                             + (((ks * 4 + hi) ^ key) * 8));
    };
    auto MMA = [&](bf16x8 (&fa)[4][2], bf16x8 (&fb)[2][2], int mo, int no) {
        __builtin_amdgcn_s_setprio(1);
        #pragma unroll
        for (int m = 0; m < 4; ++m)
            #pragma unroll
            for (int n = 0; n < 2; ++n)
                #pragma unroll
                for (int ks = 0; ks < 2; ++ks)
                    acc[mo + m][no + n] = __builtin_amdgcn_mfma_f32_16x16x32_bf16(
                        fa[m][ks], fb[n][ks], acc[mo + m][no + n], 0, 0, 0);
        __builtin_amdgcn_s_setprio(0);
    };
    // s_barrier + sched fence for memory classes (ALU/VALU/SALU/MFMA may cross)
    #define BAR() do { __builtin_amdgcn_s_barrier(); \
                       __builtin_amdgcn_sched_barrier(0xF); } while (0)

    const int NT = K >> 6;
    // ---- prologue: tile0 fully + A-halves of tile1; publish tile0, THEN read
    STAGE(0, 0, 0); STAGE(0, 1, 0); STAGE(0, 2, 0); STAGE(0, 3, 0);
    STAGE(1, 0, 1); STAGE(1, 1, 1);
    asm volatile("s_waitcnt vmcnt(4)" ::: "memory");   // own tile0 loads landed
    BAR();                                             // ...and everyone else's
    LDA(a0, 0, 0);

    int cur = 0;
    for (int t = 0; t < NT - 1; ++t) {
        const int nb = cur ^ 1;
        const int tA = (t + 2 < NT) ? t + 2 : NT - 1;  // clamped: dupes land dead
        // P1: read b0[t] AND a1[t] (a1 feeds P2); issue B0[t+1]
        STAGE(t + 1, 2, nb);
        LDB(b0, 0, cur);
        LDA(a1, 1, cur);
        MMA(a0, b0, 0, 0);
        BAR();
        // P2: no reads — MMA(a1,b0) runs on P1's reads while DS pipe is free
        STAGE(t + 1, 3, nb);
        MMA(a1, b0, 4, 0);
        BAR();
        // P3: read b1[t]; issue A0[t+2]; publish A[t+1] (vmcnt 6)
        STAGE(tA, 0, cur);
        LDB(b1, 1, cur);
        MMA(a0, b1, 0, 2);
        asm volatile("s_waitcnt vmcnt(6)" ::: "memory");
        BAR();
        // P4: read a0[t+1] (published at P3 barrier); MMA(a1,b1) on prior reads
        STAGE(tA, 1, cur);
        LDA(a0, 0, nb);
        MMA(a1, b1, 4, 2);
        asm volatile("s_waitcnt vmcnt(4)" ::: "memory");
        BAR();
        cur = nb;
    }
    // ---- epilogue: last tile, fully published by final P3/P4 waits ----
    LDB(b0, 0, cur);
    LDA(a1, 1, cur);
    MMA(a0, b0, 0, 0);
    MMA(a1, b0, 4, 0);
    LDB(b1, 1, cur);
    MMA(a0, b1, 0, 2);
    MMA(a1, b1, 4, 2);
    #undef BAR

    // ---- C write.  C/D layout: col = lane&15, row = (lane>>4)*4 + reg ----
    const int grow = bm * 256 + wm * 128 + hi * 4;
    const int gcol = bn * 256 + wn * 64 + lrow;
    if (MODE == 0) {
        float* C = (float*)Cout;
        #pragma unroll
        for (int m = 0; m < 8; ++m)
            #pragma unroll
            for (int n = 0; n < 4; ++n)
                #pragma unroll
                for (int r = 0; r < 4; ++r)
                    C[(long)(grow + m * 16 + r) * N + gcol + n * 16] = acc[m][n][r];
    } else if (MODE == 1) {
        unsigned short* C = (unsigned short*)Cout;
        #pragma unroll
        for (int m = 0; m < 8; ++m)
            #pragma unroll
            for (int n = 0; n < 4; ++n)
                #pragma unroll
                for (int r = 0; r < 4; ++r)
                    C[(long)(grow + m * 16 + r) * N + gcol + n * 16] = f2bf(acc[m][n][r]);
    } else {
        // fused SwiGLU: C holds h1 (bf16); acc = h3. write silu(h1)*h3 in place
        unsigned short* C = (unsigned short*)Cout;
        #pragma unroll
        for (int m = 0; m < 8; ++m)
            #pragma unroll
            for (int n = 0; n < 4; ++n)
                #pragma unroll
                for (int r = 0; r < 4; ++r) {
                    long idx = (long)(grow + m * 16 + r) * N + gcol + n * 16;
                    float h1v = bf2f(C[idx]);
                    float g = h1v / (1.0f + __expf(-h1v));
                    C[idx] = f2bf(g * acc[m][n][r]);
                }
    }
}

// ---- workspace layout (bytes) ----
//  [0)          W1 bf16 (90,177,536)
//  [90177536)   W3 bf16 (90,177,536)  -- later reused for W2
//  [180355072)  x  bf16 (33,554,432)
//  [213909504)  h1 bf16 (90,177,536)  -- fused swiglu written in-place by GEMM2
//  total 304,087,040
#define WS_NEEDED 304087040UL
#define DQBLK 512     // tail dequant blocks appended to GEMM1/GEMM2 dispatches

extern "C" void kernel_launch(void* const* d_in, const int* in_sizes, int n_in,
                              void* d_out, int out_size, void* d_ws, size_t ws_size,
                              hipStream_t stream) {
    const float* x   = (const float*)d_in[0];
    const int*   w1c = (const int*)d_in[1];
    const float* w1a = (const float*)d_in[2];
    const int*   w2c = (const int*)d_in[3];
    const float* w2a = (const float*)d_in[4];
    const int*   w3c = (const int*)d_in[5];
    const float* w3a = (const float*)d_in[6];

    if (ws_size < WS_NEEDED) return;   // fail loudly via validation

    char* ws = (char*)d_ws;
    unsigned short* W1 = (unsigned short*)(ws);
    unsigned short* W3 = (unsigned short*)(ws + 90177536);   // also W2 later
    unsigned short* Xb = (unsigned short*)(ws + 180355072);
    unsigned short* H1 = (unsigned short*)(ws + 213909504);

    // preamble: W1 dequant + x cast (one dispatch)
    pre_k<<<PREBLK, 256, 0, stream>>>(w1c, w1a, W1, x, Xb);

    const int g12 = (MTOK / 256) * (HID / 256);   // 688
    const int g3  = (MTOK / 256) * (DIM / 256);   // 256

    // h1 = x @ W1^T; tail blocks dequant W3 -> consumed by NEXT dispatch
    gemm256_k<1><<<g12 + DQBLK, 512, 0, stream>>>(Xb, W1, H1, MTOK, HID, DIM,
                                                  g12, w3c, w3a, W3);
    // h = silu(h1) * (x @ W3^T) in-place; tail blocks dequant W2 into W1's buf
    // (GEMM1 retired at dispatch boundary; this dispatch reads only Xb/W3/H1)
    gemm256_k<2><<<g12 + DQBLK, 512, 0, stream>>>(Xb, W3, H1, MTOK, HID, DIM,
                                                  g12, w2c, w2a, W1);
    // out = h @ W2^T (W2 lives in W1's buffer), fp32 output
    gemm256_k<0><<<g3, 512, 0, stream>>>(H1, W1, (float*)d_out, MTOK, DIM, HID,
                                         g3, nullptr, nullptr, nullptr);
}